// Round 2
// baseline (45.392 us; speedup 1.0000x reference)
//
#include <hip/hip_runtime.h>
#include <math.h>

// Problem: x[B=32][N=2048][K=8], W[N][C=32][J=16][K=8], R[N][C]
// out[b][c][j] = squash_j( sum_n softmax_n(R)[n,c] * sum_k W[n,c,j,k]*x[b,n,k] )

#define NN 2048
#define CC 32
#define JJ 16
#define KK 8
#define BB 32

// ---------------- Kernel A: per-column softmax stats (max, 1/sum) ----------------
__global__ void caps_stats(const float* __restrict__ R, float* __restrict__ M,
                           float* __restrict__ I) {
  const int c = blockIdx.x;   // 0..31
  const int t = threadIdx.x;  // 0..255
  __shared__ float red[256];

  float v[8];
#pragma unroll
  for (int i = 0; i < 8; ++i) v[i] = R[(size_t)(t + i * 256) * CC + c];

  float m = v[0];
#pragma unroll
  for (int i = 1; i < 8; ++i) m = fmaxf(m, v[i]);
  red[t] = m;
  __syncthreads();
  for (int h = 128; h >= 1; h >>= 1) {
    if (t < h) red[t] = fmaxf(red[t], red[t + h]);
    __syncthreads();
  }
  m = red[0];
  __syncthreads();

  float s = 0.f;
#pragma unroll
  for (int i = 0; i < 8; ++i) s += expf(v[i] - m);
  red[t] = s;
  __syncthreads();
  for (int h = 128; h >= 1; h >>= 1) {
    if (t < h) red[t] += red[t + h];
    __syncthreads();
  }
  if (t == 0) {
    M[c] = m;
    I[c] = 1.0f / red[0];
  }
}

// ---------------- async global->LDS helper (16B per lane) ----------------
__device__ __forceinline__ void g2l16(const float* g, float* l) {
  __builtin_amdgcn_global_load_lds((const __attribute__((address_space(1))) void*)g,
                                   (__attribute__((address_space(3))) void*)l, 16, 0, 0);
}

// ---------------- Kernel B: main streaming contraction (no W staging) ----------------
// grid 256 = 64 n-chunks x 4 c-groups; block 512 = 8 waves; 1 block/CU.
// wave ws handles n = n0 + ws*4 .. +4 (4 iterations, no barriers in loop).
// lane: j = lane&15, bo = lane>>4; acc[bi(8)][ci(8)], b = bo*8+bi, c = cg*8+ci.
// W read global->VGPR: per n, 16 dwordx4 with imm offsets (4-way lane merge, 256B/instr).
// x staged once in LDS [32][bi 8][bo 4][k 8] (conflict-free broadcast reads).
__global__ void __launch_bounds__(512) caps_main(const float* __restrict__ x,
                                                 const float* __restrict__ W,
                                                 const float* __restrict__ R,
                                                 const float* __restrict__ M,
                                                 const float* __restrict__ I,
                                                 float* __restrict__ P) {
  const int bid = blockIdx.x;
  const int cg = bid & 3;
  const int chunk = bid >> 2;
  const int n0 = chunk * 32;
  const int tid = threadIdx.x;
  const int ws = tid >> 6;
  const int lane = tid & 63;
  const int j = lane & 15;
  const int bo = lane >> 4;

  extern __shared__ float smem[];  // 16384 floats (64 KB)
  float* ldsX = smem;              // [32][256] : per n: [bi 8][bo 4][k 8]

  // ---- stage x for all 32 n of this chunk (2048 granules of 16B) ----
#pragma unroll
  for (int it = 0; it < 4; ++it) {
    int G = it * 512 + tid;
    int nl = G >> 6, r = G & 63;
    int bi = r >> 3, bo2 = (r >> 1) & 3, h = r & 1;
    int b = bo2 * 8 + bi;
    g2l16(x + (size_t)b * (NN * KK) + (size_t)(n0 + nl) * KK + h * 4,
          ldsX + (size_t)(it * 512 + ws * 64) * 4);
  }

  // softmax params for this c-octet (uniform)
  float mC[8], ivC[8];
#pragma unroll
  for (int ci = 0; ci < 8; ++ci) {
    mC[ci] = M[cg * 8 + ci];
    ivC[ci] = I[cg * 8 + ci];
  }

  float acc[8][8];
#pragma unroll
  for (int a = 0; a < 8; ++a)
#pragma unroll
    for (int b = 0; b < 8; ++b) acc[a][b] = 0.f;

  __syncthreads();

  const float4* wb4base =
      (const float4*)(W + (size_t)(n0 + ws * 4) * 4096 + cg * 1024 + j * 8);

#pragma unroll 1
  for (int nl = 0; nl < 4; ++nl) {
    const int n = n0 + ws * 4 + nl;

    // 16 in-flight global loads: full W c-octet slice for (n, j)
    const float4* wb4 = wb4base + (size_t)nl * 1024;
    float4 wv[16];
#pragma unroll
    for (int ci = 0; ci < 8; ++ci) {
      wv[2 * ci] = wb4[ci * 32];
      wv[2 * ci + 1] = wb4[ci * 32 + 1];
    }

    // x fragments from LDS (broadcast, conflict-free)
    const float* Xb = ldsX + (size_t)(ws * 4 + nl) * 256;
    float xa[8][8];
#pragma unroll
    for (int bi = 0; bi < 8; ++bi) {
      float4 lo = *(const float4*)(Xb + bi * 32 + bo * 8);
      float4 hi = *(const float4*)(Xb + bi * 32 + bo * 8 + 4);
      xa[bi][0] = lo.x; xa[bi][1] = lo.y; xa[bi][2] = lo.z; xa[bi][3] = lo.w;
      xa[bi][4] = hi.x; xa[bi][5] = hi.y; xa[bi][6] = hi.z; xa[bi][7] = hi.w;
    }

    // routing weights: exp((R - m) ) * invsum, uniform per wave
    const float* rr = R + (size_t)n * CC + cg * 8;
    float rv[8];
#pragma unroll
    for (int ci = 0; ci < 8; ++ci) rv[ci] = expf(rr[ci] - mC[ci]) * ivC[ci];

#pragma unroll
    for (int ci = 0; ci < 8; ++ci) {
      float4 wa = wv[2 * ci], wb = wv[2 * ci + 1];
      float rvv = rv[ci];
      float w0 = wa.x * rvv, w1 = wa.y * rvv, w2 = wa.z * rvv, w3 = wa.w * rvv;
      float w4 = wb.x * rvv, w5 = wb.y * rvv, w6 = wb.z * rvv, w7 = wb.w * rvv;
#pragma unroll
      for (int bi = 0; bi < 8; ++bi) {
        float a = acc[bi][ci];
        a = fmaf(w0, xa[bi][0], a);
        a = fmaf(w1, xa[bi][1], a);
        a = fmaf(w2, xa[bi][2], a);
        a = fmaf(w3, xa[bi][3], a);
        a = fmaf(w4, xa[bi][4], a);
        a = fmaf(w5, xa[bi][5], a);
        a = fmaf(w6, xa[bi][6], a);
        a = fmaf(w7, xa[bi][7], a);
        acc[bi][ci] = a;
      }
    }
  }

  // ---- cross-wave tree reduction in LDS (x region dead; 4 regions x 16KB) ----
  __syncthreads();
  float* red = smem;
#pragma unroll
  for (int half = 4; half >= 1; half >>= 1) {
    if (ws >= half && ws < 2 * half) {
      float* dst = red + (size_t)(ws - half) * 4096;
#pragma unroll
      for (int bi = 0; bi < 8; ++bi)
#pragma unroll
        for (int ci = 0; ci < 8; ++ci)
          dst[(bi * 8 + ci) * 64 + lane] = acc[bi][ci];
    }
    __syncthreads();
    if (ws < half) {
      const float* srcp = red + (size_t)ws * 4096;
#pragma unroll
      for (int bi = 0; bi < 8; ++bi)
#pragma unroll
        for (int ci = 0; ci < 8; ++ci)
          acc[bi][ci] += srcp[(bi * 8 + ci) * 64 + lane];
    }
    __syncthreads();
  }

  if (ws == 0) {
    float* dst = P + (size_t)bid * 4096;
#pragma unroll
    for (int bi = 0; bi < 8; ++bi)
#pragma unroll
      for (int ci = 0; ci < 8; ++ci)
        dst[(bi * 8 + ci) * 64 + lane] = acc[bi][ci];
  }
}

// ---------------- Kernel C: cross-chunk reduce + squash ----------------
__global__ void caps_reduce(const float* __restrict__ P, float* __restrict__ out) {
  const int g = blockIdx.x * 256 + threadIdx.x;  // b*512 + c*16 + j
  const int j = g & 15;
  const int c = (g >> 4) & 31;
  const int b = g >> 9;
  const int bo = b >> 3, bi = b & 7;
  const int cgi = c >> 3, ci = c & 7;
  const int idx = (bi * 8 + ci) * 64 + (bo * 16 + j);

  float s = 0.f;
#pragma unroll
  for (int chunk = 0; chunk < 64; ++chunk) {
    s += P[(size_t)(chunk * 4 + cgi) * 4096 + idx];
  }
  float sq = s * s;
  sq += __shfl_xor(sq, 8, 16);
  sq += __shfl_xor(sq, 4, 16);
  sq += __shfl_xor(sq, 2, 16);
  sq += __shfl_xor(sq, 1, 16);
  float ss = sq + 1e-7f;
  float scale = sqrtf(ss) / (1.0f + ss);
  out[g] = scale * s;
}

extern "C" void kernel_launch(void* const* d_in, const int* in_sizes, int n_in,
                              void* d_out, int out_size, void* d_ws, size_t ws_size,
                              hipStream_t stream) {
  const float* x = (const float*)d_in[0];   // 32*2048*8
  const float* W = (const float*)d_in[1];   // 2048*32*16*8
  const float* R = (const float*)d_in[2];   // 2048*32
  float* out = (float*)d_out;               // 32*32*16

  float* M = (float*)d_ws;                  // 32
  float* I = (float*)d_ws + 32;             // 32
  float* P = (float*)d_ws + 64;             // 256*4096 floats (4 MB)

  hipFuncSetAttribute((const void*)caps_main,
                      hipFuncAttributeMaxDynamicSharedMemorySize, 65536);

  caps_stats<<<32, 256, 0, stream>>>(R, M, I);
  caps_main<<<256, 512, 65536, stream>>>(x, W, R, M, I, P);
  caps_reduce<<<64, 256, 0, stream>>>(P, out);
}